// Round 2
// 9354.275 us; speedup vs baseline: 1.1009x; 1.1009x over previous
//
#include <hip/hip_runtime.h>
#include <hip/hip_cooperative_groups.h>
#include <float.h>
#include <math.h>

namespace cg = cooperative_groups;

#define H      1024     // LATENT
#define V      32000    // VOCAB
#define NCOND  64
#define NLIN   1024
#define ZCN    1088     // LIN + COND
#define NSTEP  128
#define NBLK   256
#define NTHR   1024
#define WPB    16       // waves per block
#define GWAVES (NBLK * WPB)   // 4096 waves total

#define DOT4(a,b) ((a).x*(b).x + (a).y*(b).y + (a).z*(b).z + (a).w*(b).w)

__device__ __forceinline__ float waveReduceSum(float v) {
#pragma unroll
    for (int off = 32; off > 0; off >>= 1)
        v += __shfl_down(v, off, 64);
    return v;
}

extern "C" __global__ void __launch_bounds__(NTHR)
decoder_kernel(const float* __restrict__ z, const float* __restrict__ cnd,
               const float* __restrict__ l1W, const float* __restrict__ l1b,
               const float* __restrict__ emb, const float* __restrict__ Wih,
               const float* __restrict__ Whh, const float* __restrict__ bih,
               const float* __restrict__ bhh, const float* __restrict__ fcW,
               const float* __restrict__ fcb, float* __restrict__ out,
               float* __restrict__ ws)
{
    cg::grid_group grid = cg::this_grid();

    // 128 KiB static weight cache: wave wv owns s_w[wv*2048 .. +2048):
    // first 1024 = its Wih row, next 1024 = its Whh row. Reused 128 steps.
    __shared__ __align__(16) float s_w[WPB * 2048];
    __shared__ __align__(16) float s_x[H];
    __shared__ __align__(16) float s_h[H];
    __shared__ float s_gate[WPB];
    __shared__ float s_cs[4];          // this block's 4 cell-state elements
    __shared__ float s_wval[WPB];
    __shared__ int   s_widx[WPB];
    __shared__ int   s_tok;

    const int tid  = threadIdx.x;
    const int lane = tid & 63;
    const int wv   = tid >> 6;
    const int bid  = blockIdx.x;
    const int gw   = (bid << 4) + wv;           // global wave id [0, 4096)

    float* ws_h    = ws;                        // H floats
    float* ws_bval = ws + H;                    // NBLK floats
    int*   ws_bidx = (int*)(ws + H + NBLK);     // NBLK ints

    // Block owns h elements [4*bid, 4*bid+4). Wave wv handles gate (wv&3)
    // of element (wv>>2)  ->  row grow in Wih/Whh (PyTorch i,f,g,o order).
    const int elem = wv >> 2;
    const int gate = wv & 3;
    const int hj   = (bid << 2) + elem;
    const int grow = gate * H + hj;

    // ---------------- prologue ----------------
    // stage this wave's Wih/Whh rows into LDS
    {
        float4* myw = (float4*)(s_w + (wv << 11));
        const float4* wi = (const float4*)(Wih + (size_t)grow * H);
        const float4* wh = (const float4*)(Whh + (size_t)grow * H);
#pragma unroll
        for (int k = 0; k < 4; ++k) {
            myw[(k << 6) + lane]       = wi[(k << 6) + lane];
            myw[256 + (k << 6) + lane] = wh[(k << 6) + lane];
        }
    }
    const float gbias = bih[grow] + bhh[grow];

    // hoist this wave's fcb entries (its 8 fc rows are fixed across steps)
    float fb[8];
#pragma unroll
    for (int i = 0; i < 8; ++i) {
        int r = gw + i * GWAVES;
        fb[i] = fcb[r < V ? r : 0];
    }

    // h0 = l1_W @ [z;c] + l1_b   (first 1024 waves, one row each)
    if (gw < H) {
        const float* wr = l1W + (size_t)gw * ZCN;
        float acc = 0.f;
        for (int k = lane; k < ZCN; k += 64) {
            float zc = (k < NLIN) ? z[k] : cnd[k - NLIN];
            acc += wr[k] * zc;
        }
        acc = waveReduceSum(acc);
        if (lane == 0) ws_h[gw] = acc + l1b[gw];
    }
    grid.sync();

    // init: h = h0, x = relu(emb[SOS=0]), c = 0
    s_h[tid] = ws_h[tid];
    {
        float e = emb[tid];
        s_x[tid] = e > 0.f ? e : 0.f;
    }
    if (tid < 4) s_cs[tid] = 0.f;
    __syncthreads();

    for (int step = 0; step < NSTEP; ++step) {
        // ---- Phase A: 16 gate dots from LDS weights ----
        {
            const float4* myw = (const float4*)(s_w + (wv << 11));
            const float4* xv = (const float4*)s_x;
            const float4* hv = (const float4*)s_h;
            float acc = 0.f;
#pragma unroll
            for (int k = 0; k < 4; ++k) {
                const int idx = (k << 6) + lane;
                float4 a  = myw[idx];
                float4 x4 = xv[idx];
                acc += DOT4(a, x4);
                float4 a2 = myw[256 + idx];
                float4 h4 = hv[idx];
                acc += DOT4(a2, h4);
            }
            acc = waveReduceSum(acc);
            if (lane == 0) s_gate[wv] = acc + gbias;
        }
        __syncthreads();

        // ---- fused LSTM cell update for this block's 4 elements ----
        if (tid < 4) {
            float gi = s_gate[(tid << 2) + 0];
            float gf = s_gate[(tid << 2) + 1];
            float gg = s_gate[(tid << 2) + 2];
            float go = s_gate[(tid << 2) + 3];
            float i_ = 1.f / (1.f + expf(-gi));
            float f_ = 1.f / (1.f + expf(-gf));
            float g_ = tanhf(gg);
            float o_ = 1.f / (1.f + expf(-go));
            float cn = f_ * s_cs[tid] + i_ * g_;
            s_cs[tid] = cn;
            ws_h[(bid << 2) + tid] = o_ * tanhf(cn);   // publish h_{t+1} slice
        }
        grid.sync();

        // ---- stage full h_{t+1} into LDS ----
        s_h[tid] = ws_h[tid];
        __syncthreads();

        // ---- Phase B: logits + argmax, 4 fc rows interleaved per wave ----
        {
            const float4* h4p = (const float4*)s_h;
            float4 hb[4];
            hb[0] = h4p[lane];
            hb[1] = h4p[64 + lane];
            hb[2] = h4p[128 + lane];
            hb[3] = h4p[192 + lane];
            float best = -FLT_MAX; int bbi = 0x7fffffff;
            float* outp = out + (size_t)step * V;

            {   // chunk 0: rows gw + {0,1,2,3}*GWAVES — all valid
                const int r = gw;
                const float4* p0 = (const float4*)(fcW + (size_t)r * H);
                const float4* p1 = p0 + (size_t)GWAVES * 256;
                const float4* p2 = p1 + (size_t)GWAVES * 256;
                const float4* p3 = p2 + (size_t)GWAVES * 256;
                float a0 = 0.f, a1 = 0.f, a2 = 0.f, a3 = 0.f;
#pragma unroll
                for (int k = 0; k < 4; ++k) {
                    const int idx = (k << 6) + lane;
                    a0 += DOT4(p0[idx], hb[k]);
                    a1 += DOT4(p1[idx], hb[k]);
                    a2 += DOT4(p2[idx], hb[k]);
                    a3 += DOT4(p3[idx], hb[k]);
                }
#pragma unroll
                for (int off = 32; off > 0; off >>= 1) {
                    a0 += __shfl_down(a0, off, 64);
                    a1 += __shfl_down(a1, off, 64);
                    a2 += __shfl_down(a2, off, 64);
                    a3 += __shfl_down(a3, off, 64);
                }
                if (lane == 0) {
                    float lg;
                    lg = a0 + fb[0]; __builtin_nontemporal_store(lg, &outp[r]);
                    if (lg > best) { best = lg; bbi = r; }
                    lg = a1 + fb[1]; __builtin_nontemporal_store(lg, &outp[r + GWAVES]);
                    if (lg > best) { best = lg; bbi = r + GWAVES; }
                    lg = a2 + fb[2]; __builtin_nontemporal_store(lg, &outp[r + 2*GWAVES]);
                    if (lg > best) { best = lg; bbi = r + 2*GWAVES; }
                    lg = a3 + fb[3]; __builtin_nontemporal_store(lg, &outp[r + 3*GWAVES]);
                    if (lg > best) { best = lg; bbi = r + 3*GWAVES; }
                }
            }
            {   // chunk 1: rows gw + {4,5,6,7}*GWAVES — slot 7 may be OOB
                const int r  = gw + 4 * GWAVES;
                const int r3 = r + 3 * GWAVES;
                const bool v3 = (r3 < V);
                const float4* p0 = (const float4*)(fcW + (size_t)r * H);
                const float4* p1 = p0 + (size_t)GWAVES * 256;
                const float4* p2 = p1 + (size_t)GWAVES * 256;
                const float4* p3 = (const float4*)(fcW + (size_t)(v3 ? r3 : 0) * H);
                float a0 = 0.f, a1 = 0.f, a2 = 0.f, a3 = 0.f;
#pragma unroll
                for (int k = 0; k < 4; ++k) {
                    const int idx = (k << 6) + lane;
                    a0 += DOT4(p0[idx], hb[k]);
                    a1 += DOT4(p1[idx], hb[k]);
                    a2 += DOT4(p2[idx], hb[k]);
                    a3 += DOT4(p3[idx], hb[k]);
                }
#pragma unroll
                for (int off = 32; off > 0; off >>= 1) {
                    a0 += __shfl_down(a0, off, 64);
                    a1 += __shfl_down(a1, off, 64);
                    a2 += __shfl_down(a2, off, 64);
                    a3 += __shfl_down(a3, off, 64);
                }
                if (lane == 0) {
                    float lg;
                    lg = a0 + fb[4]; __builtin_nontemporal_store(lg, &outp[r]);
                    if (lg > best) { best = lg; bbi = r; }
                    lg = a1 + fb[5]; __builtin_nontemporal_store(lg, &outp[r + GWAVES]);
                    if (lg > best) { best = lg; bbi = r + GWAVES; }
                    lg = a2 + fb[6]; __builtin_nontemporal_store(lg, &outp[r + 2*GWAVES]);
                    if (lg > best) { best = lg; bbi = r + 2*GWAVES; }
                    if (v3) {
                        lg = a3 + fb[7]; __builtin_nontemporal_store(lg, &outp[r3]);
                        if (lg > best) { best = lg; bbi = r3; }
                    }
                }
            }
            if (lane == 0) { s_wval[wv] = best; s_widx[wv] = bbi; }
        }
        __syncthreads();
        if (tid == 0) {
            float bv = -FLT_MAX; int bi = 0x7fffffff;
#pragma unroll
            for (int w = 0; w < WPB; ++w) {
                float v = s_wval[w]; int id = s_widx[w];
                if (v > bv || (v == bv && id < bi)) { bv = v; bi = id; }
            }
            ws_bval[bid] = bv;
            ws_bidx[bid] = bi;
        }
        grid.sync();

        // ---- token select (redundant per block) + stage next x ----
        if (wv == 0) {
            const int base = lane << 2;
            float bv = -FLT_MAX; int bi = 0x7fffffff;
#pragma unroll
            for (int k = 0; k < 4; ++k) {
                float v = ws_bval[base + k]; int id = ws_bidx[base + k];
                if (v > bv || (v == bv && id < bi)) { bv = v; bi = id; }
            }
#pragma unroll
            for (int off = 32; off > 0; off >>= 1) {
                float ov = __shfl_down(bv, off, 64);
                int   oi = __shfl_down(bi, off, 64);
                if (ov > bv || (ov == bv && oi < bi)) { bv = ov; bi = oi; }
            }
            if (lane == 0) s_tok = bi;
        }
        __syncthreads();
        {
            const float* er = emb + (size_t)s_tok * H;
            float e = er[tid];
            s_x[tid] = e > 0.f ? e : 0.f;
        }
        __syncthreads();
    }
}

extern "C" void kernel_launch(void* const* d_in, const int* in_sizes, int n_in,
                              void* d_out, int out_size, void* d_ws, size_t ws_size,
                              hipStream_t stream) {
    const float* z   = (const float*)d_in[0];
    const float* c   = (const float*)d_in[1];
    const float* l1W = (const float*)d_in[2];
    const float* l1b = (const float*)d_in[3];
    const float* emb = (const float*)d_in[4];
    const float* Wih = (const float*)d_in[5];
    const float* Whh = (const float*)d_in[6];
    const float* bih = (const float*)d_in[7];
    const float* bhh = (const float*)d_in[8];
    const float* fcW = (const float*)d_in[9];
    const float* fcb = (const float*)d_in[10];
    float* out = (float*)d_out;
    float* ws  = (float*)d_ws;

    void* args[] = { &z, &c, &l1W, &l1b, &emb, &Wih, &Whh, &bih, &bhh,
                     &fcW, &fcb, &out, &ws };
    hipLaunchCooperativeKernel((void*)decoder_kernel, dim3(NBLK), dim3(NTHR),
                               args, 0, stream);
}